// Round 2
// baseline (50414.322 us; speedup 1.0000x reference)
//
#include <hip/hip_runtime.h>
#include <hip/hip_bf16.h>
#include <hip/hip_cooperative_groups.h>

namespace cg = cooperative_groups;

typedef unsigned short u16;
typedef u16 u16x8 __attribute__((ext_vector_type(8)));

__device__ __forceinline__ float b2f(u16 u) {
    unsigned int i = ((unsigned int)u) << 16;
    return __builtin_bit_cast(float, i);
}
__device__ __forceinline__ u16 f2b(float f) {
    unsigned int b = __builtin_bit_cast(unsigned int, f);
    b += 0x7FFFu + ((b >> 16) & 1u);   // RNE
    return (u16)(b >> 16);
}

// ---------------------------------------------------------------------------
// Kernel A: Xproj[t][r] = bias[r] + dot(Wih[r,:], x_t)  for t in [0,257)
// x_t = embed[seq[t]] (fp32) for t<256, eos for t==256.  Output fp32 [257][8192].
// grid = (256, 33), block = 256 (4 waves). Each wave: 8 rows, 8 elems/lane.
// ---------------------------------------------------------------------------
__global__ void __launch_bounds__(256)
xproj_kernel(const float* __restrict__ embed, const float* __restrict__ eos,
             const int* __restrict__ seq, const float* __restrict__ W,
             const float* __restrict__ bias, float* __restrict__ Xp)
{
    __shared__ float xs[8][512];
    const int tid = threadIdx.x;
    const int t0 = blockIdx.y * 8;
    const int nt = min(8, 257 - t0);

    for (int idx = tid; idx < nt * 512; idx += 256) {
        int tt = idx >> 9, col = idx & 511;
        int t = t0 + tt;
        xs[tt][col] = (t < 256) ? embed[(size_t)seq[t] * 512 + col] : eos[col];
    }
    __syncthreads();

    const int lane = tid & 63;
    const int wv = tid >> 6;

    float xr[8][8];
#pragma unroll
    for (int tt = 0; tt < 8; ++tt) {
        *(float4*)&xr[tt][0] = *(const float4*)&xs[tt][lane * 8];
        *(float4*)&xr[tt][4] = *(const float4*)&xs[tt][lane * 8 + 4];
    }

#pragma unroll 1
    for (int rr = 0; rr < 8; ++rr) {
        int r = blockIdx.x * 32 + wv * 8 + rr;
        float wf[8];
        *(float4*)&wf[0] = *(const float4*)&W[(size_t)r * 512 + lane * 8];
        *(float4*)&wf[4] = *(const float4*)&W[(size_t)r * 512 + lane * 8 + 4];
        float acc[8];
#pragma unroll
        for (int tt = 0; tt < 8; tt++) {
            float a = 0.f;
#pragma unroll
            for (int j = 0; j < 8; j++) a = fmaf(wf[j], xr[tt][j], a);
            acc[tt] = a;
        }
#pragma unroll
        for (int tt = 0; tt < 8; tt++) {
            float a = acc[tt];
#pragma unroll
            for (int off = 32; off > 0; off >>= 1) a += __shfl_xor(a, off, 64);
            if (lane == 0 && tt < nt)
                Xp[(size_t)(t0 + tt) * 8192 + r] = a + bias[r];
        }
    }
}

// ---------------------------------------------------------------------------
// Kernel B: persistent cooperative LSTM. 256 WGs x 512 threads, 1 WG/CU.
// WG k owns h-indices [8k, 8k+8): rows {g*2048 + 8k + jj} of Whh (fp32 in
// global), converted to bf16 into LDS at each phase start (32 x 2048 = 128KB).
// h/c/gates all fp32. One grid.sync per step.
// ---------------------------------------------------------------------------
__global__ void __launch_bounds__(512, 1)
rnn_coop(const float* __restrict__ WhhA, const float* __restrict__ WhhB,
         const float* __restrict__ pWih, const float* __restrict__ pWhh,
         const float* __restrict__ pB,
         const float* __restrict__ Xp0, const float* __restrict__ Xp1,
         float* __restrict__ hbuf, float* __restrict__ out)
{
    __shared__ __align__(16) u16 wlds[32 * 2048];
    __shared__ float gsum[32];
    cg::grid_group grid = cg::this_grid();

    const int wg = blockIdx.x;
    const int tid = threadIdx.x;
    const int lane = tid & 63;
    const int wv = tid >> 6;
    float c_reg = 0.f;

    for (int t = 0; t < 524; ++t) {
        const int phase = (t < 257) ? 0 : (t < 514) ? 1 : 2;
        const bool pstart = (t == 0) || (t == 257) || (t == 514);

        if (pstart) {
            __syncthreads();
            if (phase < 2) {
                const float* W = phase ? WhhB : WhhA;
                for (int idx = tid; idx < 32 * 256; idx += 512) {
                    int p = idx << 3;                 // element offset in tile
                    int rl = p >> 11, col = p & 2047; // rl = gate*8 + jj
                    int grow = ((rl >> 3) << 11) + (wg << 3) + (rl & 7);
                    float wf[8];
                    *(float4*)&wf[0] = *(const float4*)&W[(size_t)grow * 2048 + col];
                    *(float4*)&wf[4] = *(const float4*)&W[(size_t)grow * 2048 + col + 4];
                    u16x8 s;
#pragma unroll
                    for (int j = 0; j < 8; j++) s[j] = f2b(wf[j]);
                    *(u16x8*)&wlds[p] = s;
                }
            } else {
                for (int idx = tid; idx < 32 * 256; idx += 512) {
                    int p = idx << 3;
                    int rl = p >> 11, col = p & 2047;
                    int grow = ((rl >> 3) << 11) + (wg << 3) + (rl & 7);
                    float af[8], bf[8];
                    *(float4*)&af[0] = *(const float4*)&pWih[(size_t)grow * 2048 + col];
                    *(float4*)&af[4] = *(const float4*)&pWih[(size_t)grow * 2048 + col + 4];
                    *(float4*)&bf[0] = *(const float4*)&pWhh[(size_t)grow * 2048 + col];
                    *(float4*)&bf[4] = *(const float4*)&pWhh[(size_t)grow * 2048 + col + 4];
                    u16x8 s;
#pragma unroll
                    for (int j = 0; j < 8; j++) s[j] = f2b(af[j] + bf[j]);
                    *(u16x8*)&wlds[p] = s;
                }
            }
            __syncthreads();
        }

        // prefetch the per-step input projection (4 gate values) early
        float xp0 = 0.f, xp1 = 0.f, xp2 = 0.f, xp3 = 0.f;
        if (tid < 8) {
            if (phase == 0) {
                const float* src = Xp0 + (size_t)t * 8192 + (wg << 3) + tid;
                xp0 = src[0]; xp1 = src[2048]; xp2 = src[4096]; xp3 = src[6144];
            } else if (phase == 1) {
                const float* src = Xp1 + (size_t)(t - 257) * 8192 + (wg << 3) + tid;
                xp0 = src[0]; xp1 = src[2048]; xp2 = src[4096]; xp3 = src[6144];
            } else {
                int base = (wg << 3) + tid;
                xp0 = pB[base];        xp1 = pB[base + 2048];
                xp2 = pB[base + 4096]; xp3 = pB[base + 6144];
            }
        }

        if (t > 0) {
            const float* hsrc = hbuf + ((t & 1) << 11);
            float hreg[32];
#pragma unroll
            for (int q = 0; q < 4; q++) {
                *(float4*)&hreg[q * 8]     = *(const float4*)&hsrc[(q << 9) + (lane << 3)];
                *(float4*)&hreg[q * 8 + 4] = *(const float4*)&hsrc[(q << 9) + (lane << 3) + 4];
            }
#pragma unroll
            for (int rr = 0; rr < 4; ++rr) {
                const int rl = (wv << 2) + rr;
                float acc = 0.f;
#pragma unroll
                for (int q = 0; q < 4; q++) {
                    u16x8 w8 = *(const u16x8*)&wlds[(rl << 11) + (q << 9) + (lane << 3)];
#pragma unroll
                    for (int j = 0; j < 8; j++)
                        acc = fmaf(b2f(w8[j]), hreg[(q << 3) + j], acc);
                }
#pragma unroll
                for (int off = 32; off > 0; off >>= 1) acc += __shfl_xor(acc, off, 64);
                if (lane == 0) gsum[rl] = acc;
            }
        }
        __syncthreads();

        if (tid < 8) {
            float g0 = xp0, g1 = xp1, g2 = xp2, g3 = xp3;
            if (t > 0) {
                g0 += gsum[tid];      g1 += gsum[8 + tid];
                g2 += gsum[16 + tid]; g3 += gsum[24 + tid];
            }
            float gi = 1.f / (1.f + expf(-g0));
            float gf = 1.f / (1.f + expf(-g1));
            float gc = tanhf(g2);
            float go = 1.f / (1.f + expf(-g3));
            c_reg = gf * c_reg + gi * gc;
            float h2 = go * tanhf(c_reg);
            hbuf[(((t + 1) & 1) << 11) + (wg << 3) + tid] = h2;
            if (phase == 2)
                out[(size_t)(t - 514) * 2048 + (wg << 3) + tid] = h2;
        }
        __threadfence();
        grid.sync();
        __threadfence();
    }
}

// ---------------------------------------------------------------------------
extern "C" void kernel_launch(void* const* d_in, const int* in_sizes, int n_in,
                              void* d_out, int out_size, void* d_ws, size_t ws_size,
                              hipStream_t stream) {
    const int*   in_seq   = (const int*)d_in[0];
    const int*   out_seq  = (const int*)d_in[1];
    const float* embed    = (const float*)d_in[2];
    const float* eos      = (const float*)d_in[3];
    const float* in_Wih   = (const float*)d_in[4];
    const float* in_Whh   = (const float*)d_in[5];
    const float* in_b     = (const float*)d_in[6];
    const float* out_Wih  = (const float*)d_in[7];
    const float* out_Whh  = (const float*)d_in[8];
    const float* out_b    = (const float*)d_in[9];
    const float* pg_Wih   = (const float*)d_in[10];
    const float* pg_Whh   = (const float*)d_in[11];
    const float* pg_b     = (const float*)d_in[12];

    float* Xp0  = (float*)d_ws;                       // 257*8192 fp32
    float* Xp1  = Xp0 + (size_t)257 * 8192;           // 257*8192 fp32
    float* hbuf = Xp1 + (size_t)257 * 8192;           // 2*2048 fp32

    dim3 g1(256, 33), b1(256);
    hipLaunchKernelGGL(xproj_kernel, g1, b1, 0, stream, embed, eos, in_seq,  in_Wih,  in_b,  Xp0);
    hipLaunchKernelGGL(xproj_kernel, g1, b1, 0, stream, embed, eos, out_seq, out_Wih, out_b, Xp1);

    float* out = (float*)d_out;
    void* args[] = { (void*)&in_Whh, (void*)&out_Whh, (void*)&pg_Wih, (void*)&pg_Whh,
                     (void*)&pg_b, (void*)&Xp0, (void*)&Xp1, (void*)&hbuf, (void*)&out };
    hipLaunchCooperativeKernel((const void*)rnn_coop, dim3(256), dim3(512),
                               args, 0, stream);
}

// Round 3
// 5963.425 us; speedup vs baseline: 8.4539x; 8.4539x over previous
//
#include <hip/hip_runtime.h>
#include <hip/hip_bf16.h>
#include <hip/hip_cooperative_groups.h>

typedef unsigned short u16;
typedef u16 u16x8 __attribute__((ext_vector_type(8)));

#define NBLK 256

__device__ __forceinline__ float b2f(u16 u) {
    unsigned int i = ((unsigned int)u) << 16;
    return __builtin_bit_cast(float, i);
}
__device__ __forceinline__ u16 f2b(float f) {
    unsigned int b = __builtin_bit_cast(unsigned int, f);
    b += 0x7FFFu + ((b >> 16) & 1u);   // RNE
    return (u16)(b >> 16);
}

// Lightweight grid barrier: accumulating epoch counter, agent-scope atomics,
// minimal explicit fences. Requires all NBLK blocks co-resident (cooperative
// launch). target = NBLK * (epoch+1).
__device__ __forceinline__ void gbar(unsigned int* cnt, unsigned int target) {
    __syncthreads();
    if (threadIdx.x == 0) {
        __builtin_amdgcn_fence(__ATOMIC_RELEASE, "agent");       // flush h writes
        __hip_atomic_fetch_add(cnt, 1u, __ATOMIC_RELAXED, __HIP_MEMORY_SCOPE_AGENT);
        while (__hip_atomic_load(cnt, __ATOMIC_RELAXED, __HIP_MEMORY_SCOPE_AGENT) < target)
            __builtin_amdgcn_s_sleep(2);
        __builtin_amdgcn_fence(__ATOMIC_ACQUIRE, "agent");       // inv for h reads
    }
    __syncthreads();
}

// ---------------------------------------------------------------------------
// Kernel A: Xproj[t][r] = bias[r] + dot(Wih[r,:], x_t)  for t in [0,257)
// ---------------------------------------------------------------------------
__global__ void __launch_bounds__(256)
xproj_kernel(const float* __restrict__ embed, const float* __restrict__ eos,
             const int* __restrict__ seq, const float* __restrict__ W,
             const float* __restrict__ bias, float* __restrict__ Xp)
{
    __shared__ float xs[8][512];
    const int tid = threadIdx.x;
    const int t0 = blockIdx.y * 8;
    const int nt = min(8, 257 - t0);

    for (int idx = tid; idx < nt * 512; idx += 256) {
        int tt = idx >> 9, col = idx & 511;
        int t = t0 + tt;
        xs[tt][col] = (t < 256) ? embed[(size_t)seq[t] * 512 + col] : eos[col];
    }
    __syncthreads();

    const int lane = tid & 63;
    const int wv = tid >> 6;

    float xr[8][8];
#pragma unroll
    for (int tt = 0; tt < 8; ++tt) {
        *(float4*)&xr[tt][0] = *(const float4*)&xs[tt][lane * 8];
        *(float4*)&xr[tt][4] = *(const float4*)&xs[tt][lane * 8 + 4];
    }

#pragma unroll 1
    for (int rr = 0; rr < 8; ++rr) {
        int r = blockIdx.x * 32 + wv * 8 + rr;
        float wf[8];
        *(float4*)&wf[0] = *(const float4*)&W[(size_t)r * 512 + lane * 8];
        *(float4*)&wf[4] = *(const float4*)&W[(size_t)r * 512 + lane * 8 + 4];
        float acc[8];
#pragma unroll
        for (int tt = 0; tt < 8; tt++) {
            float a = 0.f;
#pragma unroll
            for (int j = 0; j < 8; j++) a = fmaf(wf[j], xr[tt][j], a);
            acc[tt] = a;
        }
#pragma unroll
        for (int tt = 0; tt < 8; tt++) {
            float a = acc[tt];
#pragma unroll
            for (int off = 32; off > 0; off >>= 1) a += __shfl_xor(a, off, 64);
            if (lane == 0 && tt < nt)
                Xp[(size_t)(t0 + tt) * 8192 + r] = a + bias[r];
        }
    }
}

// ---------------------------------------------------------------------------
// Kernel B: persistent cooperative LSTM. 256 WGs x 512 threads, 1 WG/CU.
// WG k owns h-indices [8k, 8k+8): rows {g*2048 + 8k + jj} of Whh (fp32 in
// global), converted to bf16 into LDS at each phase start (32 x 2048 = 128KB).
// h/c/gates all fp32. One custom epoch barrier per step.
// ---------------------------------------------------------------------------
__global__ void __launch_bounds__(512, 1)
rnn_coop(const float* __restrict__ WhhA, const float* __restrict__ WhhB,
         const float* __restrict__ pWih, const float* __restrict__ pWhh,
         const float* __restrict__ pB,
         const float* __restrict__ Xp0, const float* __restrict__ Xp1,
         float* __restrict__ hbuf, unsigned int* __restrict__ barcnt,
         float* __restrict__ out)
{
    __shared__ __align__(16) u16 wlds[32 * 2048];
    __shared__ float gsum[32];

    const int wg = blockIdx.x;
    const int tid = threadIdx.x;
    const int lane = tid & 63;
    const int wv = tid >> 6;
    float c_reg = 0.f;

    for (int t = 0; t < 524; ++t) {
        const int phase = (t < 257) ? 0 : (t < 514) ? 1 : 2;
        const bool pstart = (t == 0) || (t == 257) || (t == 514);

        if (pstart) {
            __syncthreads();
            if (phase < 2) {
                const float* W = phase ? WhhB : WhhA;
                for (int idx = tid; idx < 32 * 256; idx += 512) {
                    int p = idx << 3;                 // element offset in tile
                    int rl = p >> 11, col = p & 2047; // rl = gate*8 + jj
                    int grow = ((rl >> 3) << 11) + (wg << 3) + (rl & 7);
                    float wf[8];
                    *(float4*)&wf[0] = *(const float4*)&W[(size_t)grow * 2048 + col];
                    *(float4*)&wf[4] = *(const float4*)&W[(size_t)grow * 2048 + col + 4];
                    u16x8 s;
#pragma unroll
                    for (int j = 0; j < 8; j++) s[j] = f2b(wf[j]);
                    *(u16x8*)&wlds[p] = s;
                }
            } else {
                for (int idx = tid; idx < 32 * 256; idx += 512) {
                    int p = idx << 3;
                    int rl = p >> 11, col = p & 2047;
                    int grow = ((rl >> 3) << 11) + (wg << 3) + (rl & 7);
                    float af[8], bf[8];
                    *(float4*)&af[0] = *(const float4*)&pWih[(size_t)grow * 2048 + col];
                    *(float4*)&af[4] = *(const float4*)&pWih[(size_t)grow * 2048 + col + 4];
                    *(float4*)&bf[0] = *(const float4*)&pWhh[(size_t)grow * 2048 + col];
                    *(float4*)&bf[4] = *(const float4*)&pWhh[(size_t)grow * 2048 + col + 4];
                    u16x8 s;
#pragma unroll
                    for (int j = 0; j < 8; j++) s[j] = f2b(af[j] + bf[j]);
                    *(u16x8*)&wlds[p] = s;
                }
            }
            __syncthreads();
        }

        // prefetch the per-step input projection (4 gate values) early
        float xp0 = 0.f, xp1 = 0.f, xp2 = 0.f, xp3 = 0.f;
        if (tid < 8) {
            if (phase == 0) {
                const float* src = Xp0 + (size_t)t * 8192 + (wg << 3) + tid;
                xp0 = src[0]; xp1 = src[2048]; xp2 = src[4096]; xp3 = src[6144];
            } else if (phase == 1) {
                const float* src = Xp1 + (size_t)(t - 257) * 8192 + (wg << 3) + tid;
                xp0 = src[0]; xp1 = src[2048]; xp2 = src[4096]; xp3 = src[6144];
            } else {
                int base = (wg << 3) + tid;
                xp0 = pB[base];        xp1 = pB[base + 2048];
                xp2 = pB[base + 4096]; xp3 = pB[base + 6144];
            }
        }

        if (t > 0) {
            const float* hsrc = hbuf + ((t & 1) << 11);
            float hreg[32];
#pragma unroll
            for (int q = 0; q < 4; q++) {
                *(float4*)&hreg[q * 8]     = *(const float4*)&hsrc[(q << 9) + (lane << 3)];
                *(float4*)&hreg[q * 8 + 4] = *(const float4*)&hsrc[(q << 9) + (lane << 3) + 4];
            }
#pragma unroll
            for (int rr = 0; rr < 4; ++rr) {
                const int rl = (wv << 2) + rr;
                float acc = 0.f;
#pragma unroll
                for (int q = 0; q < 4; q++) {
                    u16x8 w8 = *(const u16x8*)&wlds[(rl << 11) + (q << 9) + (lane << 3)];
#pragma unroll
                    for (int j = 0; j < 8; j++)
                        acc = fmaf(b2f(w8[j]), hreg[(q << 3) + j], acc);
                }
#pragma unroll
                for (int off = 32; off > 0; off >>= 1) acc += __shfl_xor(acc, off, 64);
                if (lane == 0) gsum[rl] = acc;
            }
        }
        __syncthreads();

        if (tid < 8) {
            float g0 = xp0, g1 = xp1, g2 = xp2, g3 = xp3;
            if (t > 0) {
                g0 += gsum[tid];      g1 += gsum[8 + tid];
                g2 += gsum[16 + tid]; g3 += gsum[24 + tid];
            }
            float gi = 1.f / (1.f + expf(-g0));
            float gf = 1.f / (1.f + expf(-g1));
            float gc = tanhf(g2);
            float go = 1.f / (1.f + expf(-g3));
            c_reg = gf * c_reg + gi * gc;
            float h2 = go * tanhf(c_reg);
            hbuf[(((t + 1) & 1) << 11) + (wg << 3) + tid] = h2;
            if (phase == 2)
                out[(size_t)(t - 514) * 2048 + (wg << 3) + tid] = h2;
        }

        gbar(barcnt, (unsigned int)(NBLK * (t + 1)));
    }
}

// ---------------------------------------------------------------------------
extern "C" void kernel_launch(void* const* d_in, const int* in_sizes, int n_in,
                              void* d_out, int out_size, void* d_ws, size_t ws_size,
                              hipStream_t stream) {
    const int*   in_seq   = (const int*)d_in[0];
    const int*   out_seq  = (const int*)d_in[1];
    const float* embed    = (const float*)d_in[2];
    const float* eos      = (const float*)d_in[3];
    const float* in_Wih   = (const float*)d_in[4];
    const float* in_Whh   = (const float*)d_in[5];
    const float* in_b     = (const float*)d_in[6];
    const float* out_Wih  = (const float*)d_in[7];
    const float* out_Whh  = (const float*)d_in[8];
    const float* out_b    = (const float*)d_in[9];
    const float* pg_Wih   = (const float*)d_in[10];
    const float* pg_Whh   = (const float*)d_in[11];
    const float* pg_b     = (const float*)d_in[12];

    float* Xp0  = (float*)d_ws;                        // 257*8192 fp32
    float* Xp1  = Xp0 + (size_t)257 * 8192;            // 257*8192 fp32
    float* hbuf = Xp1 + (size_t)257 * 8192;            // 2*2048 fp32
    unsigned int* barcnt = (unsigned int*)(hbuf + 2 * 2048 + 64); // isolated line

    hipMemsetAsync(barcnt, 0, sizeof(unsigned int), stream);

    dim3 g1(256, 33), b1(256);
    hipLaunchKernelGGL(xproj_kernel, g1, b1, 0, stream, embed, eos, in_seq,  in_Wih,  in_b,  Xp0);
    hipLaunchKernelGGL(xproj_kernel, g1, b1, 0, stream, embed, eos, out_seq, out_Wih, out_b, Xp1);

    float* out = (float*)d_out;
    void* args[] = { (void*)&in_Whh, (void*)&out_Whh, (void*)&pg_Wih, (void*)&pg_Whh,
                     (void*)&pg_b, (void*)&Xp0, (void*)&Xp1, (void*)&hbuf,
                     (void*)&barcnt, (void*)&out };
    hipLaunchCooperativeKernel((const void*)rnn_coop, dim3(NBLK), dim3(512),
                               args, 0, stream);
}

// Round 4
// 5244.458 us; speedup vs baseline: 9.6129x; 1.1371x over previous
//
#include <hip/hip_runtime.h>
#include <hip/hip_bf16.h>

typedef unsigned short u16;
typedef u16 u16x8 __attribute__((ext_vector_type(8)));
typedef unsigned long long u64;

#define NBLK 256

__device__ __forceinline__ float b2f(u16 u) {
    unsigned int i = ((unsigned int)u) << 16;
    return __builtin_bit_cast(float, i);
}
__device__ __forceinline__ u16 f2b(float f) {
    unsigned int b = __builtin_bit_cast(unsigned int, f);
    b += 0x7FFFu + ((b >> 16) & 1u);   // RNE
    return (u16)(b >> 16);
}

// ---------------------------------------------------------------------------
// Kernel A: Xproj[t][r] = bias[r] + dot(Wih[r,:], x_t)  for t in [0,257)
// grid = (256), block = 256. Each block keeps its 32 weight rows in regs
// (8 rows x 8 cols per lane) and loops over all 33 t-groups.
// ---------------------------------------------------------------------------
__global__ void __launch_bounds__(256)
xproj_kernel(const float* __restrict__ embed, const float* __restrict__ eos,
             const int* __restrict__ seq, const float* __restrict__ W,
             const float* __restrict__ bias, float* __restrict__ Xp)
{
    __shared__ float xs[8][512];
    const int tid = threadIdx.x;
    const int lane = tid & 63;
    const int wv = tid >> 6;

    float wf[8][8];
    float bs[8];
#pragma unroll
    for (int rr = 0; rr < 8; ++rr) {
        int r = blockIdx.x * 32 + wv * 8 + rr;
        *(float4*)&wf[rr][0] = *(const float4*)&W[(size_t)r * 512 + lane * 8];
        *(float4*)&wf[rr][4] = *(const float4*)&W[(size_t)r * 512 + lane * 8 + 4];
        bs[rr] = bias[r];
    }

    for (int t0 = 0; t0 < 257; t0 += 8) {
        const int nt = min(8, 257 - t0);
        __syncthreads();                       // xs reuse across iterations
        for (int idx = tid; idx < nt * 512; idx += 256) {
            int tt = idx >> 9, col = idx & 511;
            int t = t0 + tt;
            xs[tt][col] = (t < 256) ? embed[(size_t)seq[t] * 512 + col] : eos[col];
        }
        __syncthreads();

        float xr[8][8];
#pragma unroll
        for (int tt = 0; tt < 8; ++tt) {
            *(float4*)&xr[tt][0] = *(const float4*)&xs[tt][lane * 8];
            *(float4*)&xr[tt][4] = *(const float4*)&xs[tt][lane * 8 + 4];
        }

#pragma unroll
        for (int rr = 0; rr < 8; ++rr) {
            float acc[8];
#pragma unroll
            for (int tt = 0; tt < 8; tt++) {
                float a = 0.f;
#pragma unroll
                for (int j = 0; j < 8; j++) a = fmaf(wf[rr][j], xr[tt][j], a);
                acc[tt] = a;
            }
#pragma unroll
            for (int tt = 0; tt < 8; tt++) {
                float a = acc[tt];
#pragma unroll
                for (int off = 32; off > 0; off >>= 1) a += __shfl_xor(a, off, 64);
                if (lane == 0 && tt < nt)
                    Xp[(size_t)(t0 + tt) * 8192 + blockIdx.x * 32 + wv * 8 + rr] = a + bs[rr];
            }
        }
    }
}

// ---------------------------------------------------------------------------
// Kernel B: persistent LSTM. 256 WGs x 512 threads, 1 WG/CU.
// Cross-block h exchange entirely via agent-scope write-through (sc0+sc1)
// atomics -> L3 is the coherence point; NO cache-wide fences anywhere.
// Barrier: per-block flag store (vmcnt-ordered) + 256-thread flag poll.
// ---------------------------------------------------------------------------
__global__ void __launch_bounds__(512, 1)
rnn_coop(const float* __restrict__ WhhA, const float* __restrict__ WhhB,
         const float* __restrict__ pWih, const float* __restrict__ pWhh,
         const float* __restrict__ pB,
         const float* __restrict__ Xp0, const float* __restrict__ Xp1,
         float* __restrict__ hbuf, unsigned int* __restrict__ flags,
         float* __restrict__ out)
{
    __shared__ __align__(16) u16 wlds[32 * 2048];
    __shared__ __align__(16) float hs[2048];
    __shared__ float gsum[32];

    const int wg = blockIdx.x;
    const int tid = threadIdx.x;
    const int lane = tid & 63;
    const int wv = tid >> 6;
    float c_reg = 0.f;

    for (int t = 0; t < 524; ++t) {
        const int phase = (t < 257) ? 0 : (t < 514) ? 1 : 2;
        const bool pstart = (t == 0) || (t == 257) || (t == 514);

        if (pstart) {
            __syncthreads();
            if (phase < 2) {
                const float* W = phase ? WhhB : WhhA;
                for (int idx = tid; idx < 32 * 256; idx += 512) {
                    int p = idx << 3;                 // element offset in tile
                    int rl = p >> 11, col = p & 2047; // rl = gate*8 + jj
                    int grow = ((rl >> 3) << 11) + (wg << 3) + (rl & 7);
                    float wfv[8];
                    *(float4*)&wfv[0] = *(const float4*)&W[(size_t)grow * 2048 + col];
                    *(float4*)&wfv[4] = *(const float4*)&W[(size_t)grow * 2048 + col + 4];
                    u16x8 s;
#pragma unroll
                    for (int j = 0; j < 8; j++) s[j] = f2b(wfv[j]);
                    *(u16x8*)&wlds[p] = s;
                }
            } else {
                for (int idx = tid; idx < 32 * 256; idx += 512) {
                    int p = idx << 3;
                    int rl = p >> 11, col = p & 2047;
                    int grow = ((rl >> 3) << 11) + (wg << 3) + (rl & 7);
                    float af[8], bf[8];
                    *(float4*)&af[0] = *(const float4*)&pWih[(size_t)grow * 2048 + col];
                    *(float4*)&af[4] = *(const float4*)&pWih[(size_t)grow * 2048 + col + 4];
                    *(float4*)&bf[0] = *(const float4*)&pWhh[(size_t)grow * 2048 + col];
                    *(float4*)&bf[4] = *(const float4*)&pWhh[(size_t)grow * 2048 + col + 4];
                    u16x8 s;
#pragma unroll
                    for (int j = 0; j < 8; j++) s[j] = f2b(af[j] + bf[j]);
                    *(u16x8*)&wlds[p] = s;
                }
            }
            __syncthreads();
        }

        // per-step input projection (4 gate values)
        float xp0 = 0.f, xp1 = 0.f, xp2 = 0.f, xp3 = 0.f;
        if (tid < 8) {
            if (phase == 0) {
                const float* src = Xp0 + (size_t)t * 8192 + (wg << 3) + tid;
                xp0 = src[0]; xp1 = src[2048]; xp2 = src[4096]; xp3 = src[6144];
            } else if (phase == 1) {
                const float* src = Xp1 + (size_t)(t - 257) * 8192 + (wg << 3) + tid;
                xp0 = src[0]; xp1 = src[2048]; xp2 = src[4096]; xp3 = src[6144];
            } else {
                int base = (wg << 3) + tid;
                xp0 = pB[base];        xp1 = pB[base + 2048];
                xp2 = pB[base + 4096]; xp3 = pB[base + 6144];
            }
        }

        if (t > 0) {
            // stage h (2048 f32) into LDS via agent-scope loads (bypass L1/L2)
            const u64* hsrc = (const u64*)(hbuf + ((t & 1) << 11));
            u64* hd = (u64*)hs;
#pragma unroll
            for (int q = 0; q < 2; ++q) {
                int i = tid + (q << 9);
                hd[i] = __hip_atomic_load(&hsrc[i], __ATOMIC_RELAXED,
                                          __HIP_MEMORY_SCOPE_AGENT);
            }
            __syncthreads();

            float hreg[32];
#pragma unroll
            for (int q = 0; q < 4; q++) {
                *(float4*)&hreg[q * 8]     = *(const float4*)&hs[(q << 9) + (lane << 3)];
                *(float4*)&hreg[q * 8 + 4] = *(const float4*)&hs[(q << 9) + (lane << 3) + 4];
            }
#pragma unroll
            for (int rr = 0; rr < 4; ++rr) {
                const int rl = (wv << 2) + rr;
                float acc = 0.f;
#pragma unroll
                for (int q = 0; q < 4; q++) {
                    u16x8 w8 = *(const u16x8*)&wlds[(rl << 11) + (q << 9) + (lane << 3)];
#pragma unroll
                    for (int j = 0; j < 8; j++)
                        acc = fmaf(b2f(w8[j]), hreg[(q << 3) + j], acc);
                }
#pragma unroll
                for (int off = 32; off > 0; off >>= 1) acc += __shfl_xor(acc, off, 64);
                if (lane == 0) gsum[rl] = acc;
            }
        }
        __syncthreads();

        if (tid < 8) {
            float g0 = xp0, g1 = xp1, g2 = xp2, g3 = xp3;
            if (t > 0) {
                g0 += gsum[tid];      g1 += gsum[8 + tid];
                g2 += gsum[16 + tid]; g3 += gsum[24 + tid];
            }
            float gi = 1.f / (1.f + expf(-g0));
            float gf = 1.f / (1.f + expf(-g1));
            float gc = tanhf(g2);
            float go = 1.f / (1.f + expf(-g3));
            c_reg = gf * c_reg + gi * gc;
            float h2 = go * tanhf(c_reg);
            // write-through store: lands in L3 (coherence point)
            __hip_atomic_store(&hbuf[(((t + 1) & 1) << 11) + (wg << 3) + tid], h2,
                               __ATOMIC_RELAXED, __HIP_MEMORY_SCOPE_AGENT);
            if (phase == 2)
                out[(size_t)(t - 514) * 2048 + (wg << 3) + tid] = h2;
        }

        // ---- fence-free barrier ----
        if (wv == 0) {
            // h stores are write-through; vmcnt ack => visible at L3
            asm volatile("s_waitcnt vmcnt(0)" ::: "memory");
            if (tid == 0)
                __hip_atomic_store(&flags[wg], (unsigned int)(t + 1),
                                   __ATOMIC_RELAXED, __HIP_MEMORY_SCOPE_AGENT);
        }
        if (tid < NBLK) {
            while (__hip_atomic_load(&flags[tid], __ATOMIC_RELAXED,
                                     __HIP_MEMORY_SCOPE_AGENT) < (unsigned int)(t + 1))
                __builtin_amdgcn_s_sleep(1);
        }
        __syncthreads();
    }
}

// ---------------------------------------------------------------------------
extern "C" void kernel_launch(void* const* d_in, const int* in_sizes, int n_in,
                              void* d_out, int out_size, void* d_ws, size_t ws_size,
                              hipStream_t stream) {
    const int*   in_seq   = (const int*)d_in[0];
    const int*   out_seq  = (const int*)d_in[1];
    const float* embed    = (const float*)d_in[2];
    const float* eos      = (const float*)d_in[3];
    const float* in_Wih   = (const float*)d_in[4];
    const float* in_Whh   = (const float*)d_in[5];
    const float* in_b     = (const float*)d_in[6];
    const float* out_Wih  = (const float*)d_in[7];
    const float* out_Whh  = (const float*)d_in[8];
    const float* out_b    = (const float*)d_in[9];
    const float* pg_Wih   = (const float*)d_in[10];
    const float* pg_Whh   = (const float*)d_in[11];
    const float* pg_b     = (const float*)d_in[12];

    float* Xp0  = (float*)d_ws;                        // 257*8192 fp32
    float* Xp1  = Xp0 + (size_t)257 * 8192;            // 257*8192 fp32
    float* hbuf = Xp1 + (size_t)257 * 8192;            // 2*2048 fp32
    unsigned int* flags = (unsigned int*)(hbuf + 2 * 2048 + 64);  // 256 dwords

    hipMemsetAsync(flags, 0, NBLK * sizeof(unsigned int), stream);

    dim3 g1(256), b1(256);
    hipLaunchKernelGGL(xproj_kernel, g1, b1, 0, stream, embed, eos, in_seq,  in_Wih,  in_b,  Xp0);
    hipLaunchKernelGGL(xproj_kernel, g1, b1, 0, stream, embed, eos, out_seq, out_Wih, out_b, Xp1);

    float* out = (float*)d_out;
    void* args[] = { (void*)&in_Whh, (void*)&out_Whh, (void*)&pg_Wih, (void*)&pg_Whh,
                     (void*)&pg_b, (void*)&Xp0, (void*)&Xp1, (void*)&hbuf,
                     (void*)&flags, (void*)&out };
    hipLaunchCooperativeKernel((const void*)rnn_coop, dim3(NBLK), dim3(512),
                               args, 0, stream);
}

// Round 5
// 2298.141 us; speedup vs baseline: 21.9370x; 2.2820x over previous
//
#include <hip/hip_runtime.h>
#include <hip/hip_bf16.h>

typedef unsigned short u16;
typedef u16 u16x4 __attribute__((ext_vector_type(4)));
typedef u16 u16x8 __attribute__((ext_vector_type(8)));
typedef unsigned long long u64;

#define NBLK 256
#define SENT 0xFFFFFFFFu

__device__ __forceinline__ float b2f(u16 u) {
    unsigned int i = ((unsigned int)u) << 16;
    return __builtin_bit_cast(float, i);
}
__device__ __forceinline__ u16 f2b(float f) {
    unsigned int b = __builtin_bit_cast(unsigned int, f);
    b += 0x7FFFu + ((b >> 16) & 1u);   // RNE
    return (u16)(b >> 16);
}
__device__ __forceinline__ float sigm(float x) {
    return 1.f / (1.f + __expf(-x));       // x->-inf: exp=inf -> 0; x->+inf: -> 1
}
__device__ __forceinline__ float tanh_fast(float x) {
    float a = fabsf(x);
    float e = __expf(-2.f * a);            // in (0,1], never inf
    float r = (1.f - e) / (1.f + e);
    return copysignf(r, x);
}

// ---------------------------------------------------------------------------
// Kernel A (round-3 version): Xproj[t][r] = bias[r] + dot(Wih[r,:], x_t)
// grid = (256, 33), block = 256.
// ---------------------------------------------------------------------------
__global__ void __launch_bounds__(256)
xproj_kernel(const float* __restrict__ embed, const float* __restrict__ eos,
             const int* __restrict__ seq, const float* __restrict__ W,
             const float* __restrict__ bias, float* __restrict__ Xp)
{
    __shared__ float xs[8][512];
    const int tid = threadIdx.x;
    const int t0 = blockIdx.y * 8;
    const int nt = min(8, 257 - t0);

    for (int idx = tid; idx < nt * 512; idx += 256) {
        int tt = idx >> 9, col = idx & 511;
        int t = t0 + tt;
        xs[tt][col] = (t < 256) ? embed[(size_t)seq[t] * 512 + col] : eos[col];
    }
    __syncthreads();

    const int lane = tid & 63;
    const int wv = tid >> 6;

    float xr[8][8];
#pragma unroll
    for (int tt = 0; tt < 8; ++tt) {
        *(float4*)&xr[tt][0] = *(const float4*)&xs[tt][lane * 8];
        *(float4*)&xr[tt][4] = *(const float4*)&xs[tt][lane * 8 + 4];
    }

#pragma unroll 1
    for (int rr = 0; rr < 8; ++rr) {
        int r = blockIdx.x * 32 + wv * 8 + rr;
        float wf[8];
        *(float4*)&wf[0] = *(const float4*)&W[(size_t)r * 512 + lane * 8];
        *(float4*)&wf[4] = *(const float4*)&W[(size_t)r * 512 + lane * 8 + 4];
        float acc[8];
#pragma unroll
        for (int tt = 0; tt < 8; tt++) {
            float a = 0.f;
#pragma unroll
            for (int j = 0; j < 8; j++) a = fmaf(wf[j], xr[tt][j], a);
            acc[tt] = a;
        }
#pragma unroll
        for (int tt = 0; tt < 8; tt++) {
            float a = acc[tt];
#pragma unroll
            for (int off = 32; off > 0; off >>= 1) a += __shfl_xor(a, off, 64);
            if (lane == 0 && tt < nt)
                Xp[(size_t)(t0 + tt) * 8192 + r] = a + bias[r];
        }
    }
}

// ---------------------------------------------------------------------------
// Kernel B: persistent LSTM, barrier-free. 256 WGs x 512 threads, 1 WG/CU.
// Each step t stores its 8 h values to a FRESH region hseq[t][2048]
// (write-through agent scope). Consumers poll their own dwords of
// hseq[t-1] against the 0xFF NaN sentinel -- data arrival IS the sync.
// No flags, no vmcnt drains, no grid barrier.
// ---------------------------------------------------------------------------
__global__ void __launch_bounds__(512, 1)
rnn_coop(const float* __restrict__ WhhA, const float* __restrict__ WhhB,
         const float* __restrict__ pWih, const float* __restrict__ pWhh,
         const float* __restrict__ pB,
         const float* __restrict__ Xp0, const float* __restrict__ Xp1,
         float* __restrict__ hseq, float* __restrict__ out)
{
    __shared__ __align__(16) u16 wlds[32 * 2048];
    __shared__ __align__(16) float hs[2048];
    __shared__ float gsum[32];

    const int wg = blockIdx.x;
    const int tid = threadIdx.x;
    const int lane = tid & 63;
    const int wv = tid >> 6;
    float c_reg = 0.f;

    for (int t = 0; t < 524; ++t) {
        const int phase = (t < 257) ? 0 : (t < 514) ? 1 : 2;
        const bool pstart = (t == 0) || (t == 257) || (t == 514);

        if (pstart) {
            __syncthreads();
            if (phase < 2) {
                const float* W = phase ? WhhB : WhhA;
                for (int idx = tid; idx < 32 * 256; idx += 512) {
                    int p = idx << 3;                 // element offset in tile
                    int rl = p >> 11, col = p & 2047; // rl = gate*8 + jj
                    int grow = ((rl >> 3) << 11) + (wg << 3) + (rl & 7);
                    float wfv[8];
                    *(float4*)&wfv[0] = *(const float4*)&W[(size_t)grow * 2048 + col];
                    *(float4*)&wfv[4] = *(const float4*)&W[(size_t)grow * 2048 + col + 4];
                    u16x8 s;
#pragma unroll
                    for (int j = 0; j < 8; j++) s[j] = f2b(wfv[j]);
                    *(u16x8*)&wlds[p] = s;
                }
            } else {
                for (int idx = tid; idx < 32 * 256; idx += 512) {
                    int p = idx << 3;
                    int rl = p >> 11, col = p & 2047;
                    int grow = ((rl >> 3) << 11) + (wg << 3) + (rl & 7);
                    float af[8], bf[8];
                    *(float4*)&af[0] = *(const float4*)&pWih[(size_t)grow * 2048 + col];
                    *(float4*)&af[4] = *(const float4*)&pWih[(size_t)grow * 2048 + col + 4];
                    *(float4*)&bf[0] = *(const float4*)&pWhh[(size_t)grow * 2048 + col];
                    *(float4*)&bf[4] = *(const float4*)&pWhh[(size_t)grow * 2048 + col + 4];
                    u16x8 s;
#pragma unroll
                    for (int j = 0; j < 8; j++) s[j] = f2b(af[j] + bf[j]);
                    *(u16x8*)&wlds[p] = s;
                }
            }
            __syncthreads();
        }

        // per-step input projection (4 gate values), overlapped with poll
        float xp0 = 0.f, xp1 = 0.f, xp2 = 0.f, xp3 = 0.f;
        if (tid < 8) {
            if (phase == 0) {
                const float* src = Xp0 + (size_t)t * 8192 + (wg << 3) + tid;
                xp0 = src[0]; xp1 = src[2048]; xp2 = src[4096]; xp3 = src[6144];
            } else if (phase == 1) {
                const float* src = Xp1 + (size_t)(t - 257) * 8192 + (wg << 3) + tid;
                xp0 = src[0]; xp1 = src[2048]; xp2 = src[4096]; xp3 = src[6144];
            } else {
                int base = (wg << 3) + tid;
                xp0 = pB[base];        xp1 = pB[base + 2048];
                xp2 = pB[base + 4096]; xp3 = pB[base + 6144];
            }
        }

        if (t > 0) {
            // poll own 4 dwords of hseq[t-1] until they stop being sentinel,
            // then stash into LDS. Data arrival IS the barrier.
            const u64* src = (const u64*)(hseq + (size_t)(t - 1) * 2048) + (tid << 1);
            u64 a = __hip_atomic_load(&src[0], __ATOMIC_RELAXED, __HIP_MEMORY_SCOPE_AGENT);
            while ((unsigned)a == SENT || (unsigned)(a >> 32) == SENT)
                a = __hip_atomic_load(&src[0], __ATOMIC_RELAXED, __HIP_MEMORY_SCOPE_AGENT);
            u64 b = __hip_atomic_load(&src[1], __ATOMIC_RELAXED, __HIP_MEMORY_SCOPE_AGENT);
            while ((unsigned)b == SENT || (unsigned)(b >> 32) == SENT)
                b = __hip_atomic_load(&src[1], __ATOMIC_RELAXED, __HIP_MEMORY_SCOPE_AGENT);
            ((u64*)hs)[(tid << 1) + 0] = a;
            ((u64*)hs)[(tid << 1) + 1] = b;
            __syncthreads();

            // conflict-free 16B/lane chunked reads
            float hreg[32];
#pragma unroll
            for (int q = 0; q < 8; q++)
                *(float4*)&hreg[q * 4] = *(const float4*)&hs[(q << 8) + (lane << 2)];
#pragma unroll
            for (int rr = 0; rr < 4; ++rr) {
                const int rl = (wv << 2) + rr;
                float acc = 0.f;
#pragma unroll
                for (int q = 0; q < 8; q++) {
                    u16x4 w4 = *(const u16x4*)&wlds[(rl << 11) + (q << 8) + (lane << 2)];
#pragma unroll
                    for (int j = 0; j < 4; j++)
                        acc = fmaf(b2f(w4[j]), hreg[(q << 2) + j], acc);
                }
#pragma unroll
                for (int off = 32; off > 0; off >>= 1) acc += __shfl_xor(acc, off, 64);
                if (lane == 0) gsum[rl] = acc;
            }
        }
        __syncthreads();

        if (tid < 8) {
            float g0 = xp0, g1 = xp1, g2 = xp2, g3 = xp3;
            if (t > 0) {
                g0 += gsum[tid];      g1 += gsum[8 + tid];
                g2 += gsum[16 + tid]; g3 += gsum[24 + tid];
            }
            float gi = sigm(g0);
            float gf = sigm(g1);
            float gc = tanh_fast(g2);
            float go = sigm(g3);
            c_reg = gf * c_reg + gi * gc;
            float h2 = go * tanh_fast(c_reg);
            // write-through store to the fresh region: lands in L3, becomes
            // visible to pollers; never NaN, so sentinel test is sound.
            __hip_atomic_store(&hseq[(size_t)t * 2048 + (wg << 3) + tid], h2,
                               __ATOMIC_RELAXED, __HIP_MEMORY_SCOPE_AGENT);
            if (phase == 2)
                out[(size_t)(t - 514) * 2048 + (wg << 3) + tid] = h2;
        }
        // no barrier
    }
}

// ---------------------------------------------------------------------------
extern "C" void kernel_launch(void* const* d_in, const int* in_sizes, int n_in,
                              void* d_out, int out_size, void* d_ws, size_t ws_size,
                              hipStream_t stream) {
    const int*   in_seq   = (const int*)d_in[0];
    const int*   out_seq  = (const int*)d_in[1];
    const float* embed    = (const float*)d_in[2];
    const float* eos      = (const float*)d_in[3];
    const float* in_Wih   = (const float*)d_in[4];
    const float* in_Whh   = (const float*)d_in[5];
    const float* in_b     = (const float*)d_in[6];
    const float* out_Wih  = (const float*)d_in[7];
    const float* out_Whh  = (const float*)d_in[8];
    const float* out_b    = (const float*)d_in[9];
    const float* pg_Wih   = (const float*)d_in[10];
    const float* pg_Whh   = (const float*)d_in[11];
    const float* pg_b     = (const float*)d_in[12];

    float* Xp0  = (float*)d_ws;                        // 257*8192 fp32
    float* Xp1  = Xp0 + (size_t)257 * 8192;            // 257*8192 fp32
    float* hseq = Xp1 + (size_t)257 * 8192;            // 524*2048 fp32

    // NaN sentinel (h is never NaN); fresh region per step -> no reuse races
    hipMemsetAsync(hseq, 0xFF, (size_t)524 * 2048 * sizeof(float), stream);

    dim3 g1(256, 33), b1(256);
    hipLaunchKernelGGL(xproj_kernel, g1, b1, 0, stream, embed, eos, in_seq,  in_Wih,  in_b,  Xp0);
    hipLaunchKernelGGL(xproj_kernel, g1, b1, 0, stream, embed, eos, out_seq, out_Wih, out_b, Xp1);

    float* out = (float*)d_out;
    void* args[] = { (void*)&in_Whh, (void*)&out_Whh, (void*)&pg_Wih, (void*)&pg_Whh,
                     (void*)&pg_b, (void*)&Xp0, (void*)&Xp1, (void*)&hseq, (void*)&out };
    hipLaunchCooperativeKernel((const void*)rnn_coop, dim3(NBLK), dim3(512),
                               args, 0, stream);
}